// Round 1
// baseline (521.813 us; speedup 1.0000x reference)
//
#include <hip/hip_runtime.h>

// Fused gated aggregator:
//   gates = sigmoid(nodes @ Wg + bg); data = nodes @ Wt + bt
//   out[B,D] = owner_masks(float) @ (data * gates)
// Single pass over nodes (256 MB) + masks (256 MB); bf16 MFMA, fp32 accum.

#define NTOT   500000
#define NBLK   512
#define NCHUNK 15625   // NTOT / 32, exact

typedef __attribute__((ext_vector_type(8))) unsigned short ushort8;
typedef __bf16 bf16x8 __attribute__((ext_vector_type(8)));
typedef __attribute__((ext_vector_type(4))) float f32x4;

static __device__ __forceinline__ unsigned short f2bf(float f) {
  unsigned int u = __float_as_uint(f);
  u += 0x7fffu + ((u >> 16) & 1u);       // RNE
  return (unsigned short)(u >> 16);
}

static __device__ __forceinline__ unsigned long long pack4(unsigned short a, unsigned short b,
                                                           unsigned short c, unsigned short d) {
  return (unsigned long long)a | ((unsigned long long)b << 16) |
         ((unsigned long long)c << 32) | ((unsigned long long)d << 48);
}

template <bool ATOMIC>
__global__ __launch_bounds__(256, 2)
void agg_main(const float* __restrict__ nodes, const int* __restrict__ masks,
              const float* __restrict__ Wt, const float* __restrict__ bt,
              const float* __restrict__ Wg, const float* __restrict__ bg,
              float* __restrict__ outp) {
  // LDS: strides padded so wave16 row-strided MFMA-fragment reads are <=2-way bank aliased
  __shared__ __align__(16) unsigned short nodes_s[32][136];  // [node][s]
  __shared__ __align__(16) unsigned short mask_s[128][40];   // [b][node]
  __shared__ __align__(16) unsigned short vt_s[128][40];     // [d][node] (V transposed)

  const int tid = threadIdx.x;
  const int lane = tid & 63;
  const int w = tid >> 6;    // wave 0..3
  const int q = lane >> 4;   // quad 0..3
  const int r = lane & 15;

  // ---- preload W as B-operand fragments (kept in VGPRs), + biases ----
  // B-frag mapping for 16x16x32: n = lane&15, k = quad*8 + j
  bf16x8 Wf[2][4][2];  // [data/gate][ks][nt]
  float btr[2], bgr[2];
#pragma unroll
  for (int nt = 0; nt < 2; ++nt) {
    const int d = w * 32 + nt * 16 + r;
    btr[nt] = bt[d];
    bgr[nt] = bg[d];
#pragma unroll
    for (int ks = 0; ks < 4; ++ks) {
      ushort8 ft, fg;
#pragma unroll
      for (int j = 0; j < 8; ++j) {
        const int k = ks * 32 + q * 8 + j;  // s index
        ft[j] = f2bf(Wt[k * 128 + d]);
        fg[j] = f2bf(Wg[k * 128 + d]);
      }
      Wf[0][ks][nt] = __builtin_bit_cast(bf16x8, ft);
      Wf[1][ks][nt] = __builtin_bit_cast(bf16x8, fg);
    }
  }

  // pooling accumulators: wave w owns out rows (w>>1)*64.., cols (w&1)*64..
  f32x4 acc[4][4];
  const f32x4 fzero = {0.f, 0.f, 0.f, 0.f};
#pragma unroll
  for (int i = 0; i < 4; ++i)
#pragma unroll
    for (int j = 0; j < 4; ++j) acc[i][j] = fzero;

  const int bid = blockIdx.x;
  const int c0 = (int)(((long long)bid * NCHUNK) / NBLK);
  const int c1 = (int)(((long long)(bid + 1) * NCHUNK) / NBLK);

  float4 nf[4];
  int4 mi[4];
  auto issue = [&](int c) {
    const int k0 = c * 32;
#pragma unroll
    for (int it = 0; it < 4; ++it) {
      const int flat = it * 256 + tid;
      const int nrow = flat >> 5, nc4 = flat & 31;            // 32 rows x 32 float4
      nf[it] = *(const float4*)(nodes + (size_t)(k0 + nrow) * 128 + nc4 * 4);
      const int mrow = flat >> 3, mc4 = flat & 7;             // 128 rows x 8 int4
      mi[it] = *(const int4*)(masks + (size_t)mrow * NTOT + k0 + mc4 * 4);
    }
  };

  if (c0 < c1) issue(c0);

  for (int c = c0; c < c1; ++c) {
    __syncthreads();  // previous chunk's pooling reads done
    // ---- registers -> LDS (with fp32->bf16 / int->bf16 convert) ----
#pragma unroll
    for (int it = 0; it < 4; ++it) {
      const int flat = it * 256 + tid;
      const int nrow = flat >> 5, nc4 = flat & 31;
      *(unsigned long long*)&nodes_s[nrow][nc4 * 4] =
          pack4(f2bf(nf[it].x), f2bf(nf[it].y), f2bf(nf[it].z), f2bf(nf[it].w));
      const int mrow = flat >> 3, mc4 = flat & 7;
      *(unsigned long long*)&mask_s[mrow][mc4 * 4] =
          pack4(f2bf((float)mi[it].x), f2bf((float)mi[it].y),
                f2bf((float)mi[it].z), f2bf((float)mi[it].w));
    }
    __syncthreads();
    if (c + 1 < c1) issue(c + 1);  // prefetch next chunk under compute

    // ---- GEMM1: [32 nodes x 128 s] @ W[128 s x {data,gate} cols] ----
    f32x4 aD[2][2], aG[2][2];
#pragma unroll
    for (int i = 0; i < 2; ++i)
#pragma unroll
      for (int j = 0; j < 2; ++j) { aD[i][j] = fzero; aG[i][j] = fzero; }
#pragma unroll
    for (int ks = 0; ks < 4; ++ks) {
      // A-frag: m = lane&15 (+16*mt), k = ks*32 + quad*8 + j
      bf16x8 a0 = *(const bf16x8*)&nodes_s[r][ks * 32 + q * 8];
      bf16x8 a1 = *(const bf16x8*)&nodes_s[16 + r][ks * 32 + q * 8];
#pragma unroll
      for (int nt = 0; nt < 2; ++nt) {
        aD[0][nt] = __builtin_amdgcn_mfma_f32_16x16x32_bf16(a0, Wf[0][ks][nt], aD[0][nt], 0, 0, 0);
        aD[1][nt] = __builtin_amdgcn_mfma_f32_16x16x32_bf16(a1, Wf[0][ks][nt], aD[1][nt], 0, 0, 0);
        aG[0][nt] = __builtin_amdgcn_mfma_f32_16x16x32_bf16(a0, Wf[1][ks][nt], aG[0][nt], 0, 0, 0);
        aG[1][nt] = __builtin_amdgcn_mfma_f32_16x16x32_bf16(a1, Wf[1][ks][nt], aG[1][nt], 0, 0, 0);
      }
    }

    // ---- epilogue: V = (data+bt)*sigmoid(gate+bg), write V^T[d][node] ----
    // C/D layout: col = lane&15, row = quad*4 + reg
#pragma unroll
    for (int mt = 0; mt < 2; ++mt)
#pragma unroll
      for (int nt = 0; nt < 2; ++nt) {
        const int d = w * 32 + nt * 16 + r;
        unsigned short t[4];
#pragma unroll
        for (int reg = 0; reg < 4; ++reg) {
          const float x = aD[mt][nt][reg] + btr[nt];
          const float g = aG[mt][nt][reg] + bgr[nt];
          t[reg] = f2bf(x / (1.f + __expf(-g)));
        }
        *(unsigned long long*)&vt_s[d][mt * 16 + q * 4] = pack4(t[0], t[1], t[2], t[3]);
      }
    __syncthreads();

    // ---- pooling: out[b][d] += mask[b][node] * V[node][d], K=32 ----
    const int mb = (w >> 1) * 64, nb = (w & 1) * 64;
    bf16x8 bfr[4];
#pragma unroll
    for (int nt = 0; nt < 4; ++nt)
      bfr[nt] = *(const bf16x8*)&vt_s[nb + nt * 16 + r][q * 8];
#pragma unroll
    for (int mt = 0; mt < 4; ++mt) {
      bf16x8 af = *(const bf16x8*)&mask_s[mb + mt * 16 + r][q * 8];
#pragma unroll
      for (int nt = 0; nt < 4; ++nt)
        acc[mt][nt] = __builtin_amdgcn_mfma_f32_16x16x32_bf16(af, bfr[nt], acc[mt][nt], 0, 0, 0);
    }
  }

  // ---- write per-block partial (or atomic accumulate) ----
#pragma unroll
  for (int mt = 0; mt < 4; ++mt)
#pragma unroll
    for (int nt = 0; nt < 4; ++nt)
#pragma unroll
      for (int reg = 0; reg < 4; ++reg) {
        const int b = (w >> 1) * 64 + mt * 16 + q * 4 + reg;
        const int d = (w & 1) * 64 + nt * 16 + r;
        if (ATOMIC)
          atomicAdd(&outp[b * 128 + d], acc[mt][nt][reg]);
        else
          outp[(size_t)bid * 16384 + b * 128 + d] = acc[mt][nt][reg];
      }
}

__global__ __launch_bounds__(256)
void agg_reduce(const float* __restrict__ part, float* __restrict__ out) {
  // 512 blocks x 256 thr = 131072 = 8 groups x 16384 outputs; 64 partials each
  const int gid = blockIdx.x * 256 + threadIdx.x;
  const int i = gid & 16383;
  const int grp = gid >> 14;
  const float* p = part + (size_t)grp * 64 * 16384 + i;
  float s = 0.f;
#pragma unroll 8
  for (int g = 0; g < 64; ++g) s += p[(size_t)g * 16384];
  atomicAdd(&out[i], s);
}

extern "C" void kernel_launch(void* const* d_in, const int* in_sizes, int n_in,
                              void* d_out, int out_size, void* d_ws, size_t ws_size,
                              hipStream_t stream) {
  const float* nodes = (const float*)d_in[0];
  const int*   masks = (const int*)d_in[1];
  const float* Wt    = (const float*)d_in[2];
  const float* bt    = (const float*)d_in[3];
  const float* Wg    = (const float*)d_in[4];
  const float* bg    = (const float*)d_in[5];
  float* out = (float*)d_out;

  hipMemsetAsync(d_out, 0, (size_t)out_size * sizeof(float), stream);

  const size_t need = (size_t)NBLK * 16384 * sizeof(float);
  if (ws_size >= need) {
    agg_main<false><<<NBLK, 256, 0, stream>>>(nodes, masks, Wt, bt, Wg, bg, (float*)d_ws);
    agg_reduce<<<512, 256, 0, stream>>>((const float*)d_ws, out);
  } else {
    agg_main<true><<<NBLK, 256, 0, stream>>>(nodes, masks, Wt, bt, Wg, bg, out);
  }
}